// Round 8
// baseline (158.906 us; speedup 1.0000x reference)
//
#include <hip/hip_runtime.h>
#include <math.h>

#define MS 32
#define NN 1024
#define HH 64
#define CC 10
#define SLOPEF 0.2f

typedef __attribute__((ext_vector_type(8))) short bf16x8;
typedef __attribute__((ext_vector_type(4))) float f32x4;
typedef __attribute__((ext_vector_type(4))) unsigned int u32x4;

// Split fp32 into hi/lo bf16 (truncation; lo captures residual of hi).
__device__ __forceinline__ void split2(float v, unsigned short& hi, unsigned short& lo) {
    unsigned u = __builtin_bit_cast(unsigned, v);
    hi = (unsigned short)(u >> 16);
    float hf = __builtin_bit_cast(float, u & 0xFFFF0000u);
    float l = v - hf;
    lo = (unsigned short)(__builtin_bit_cast(unsigned, l) >> 16);
}

__device__ __forceinline__ float bf16_to_f32(unsigned short h) {
    return __builtin_bit_cast(float, (unsigned)h << 16);
}

// ---------------------------------------------------------------------------
// Pre-split w_gnn into per-64k-chunk SWIZZLED LDS IMAGES (8 KB/chunk each
// for hi and lo). Image byte layout == gemm's LDS Bhi/Blo layout:
//   byte = (col*128 + k_local*2) ^ ((col&7)<<4)
// ---------------------------------------------------------------------------
__global__ __launch_bounds__(256) void split_B_sel(
    const float* __restrict__ B0, const float* __restrict__ B1,
    const float* __restrict__ B2, const int* __restrict__ flag,
    unsigned short* __restrict__ dh, unsigned short* __restrict__ dl)
{
    int vf = flag[0];
    const float* B = (vf == 0) ? B0 : (vf == 1 ? B1 : B2);
    int c = blockIdx.x;
    const float* src = B + (long)c * 64 * HH;
    unsigned short* dh_img = dh + (long)c * 4096;
    unsigned short* dl_img = dl + (long)c * 4096;

    __shared__ float tile[64][65];
    const int t = threadIdx.x;
    #pragma unroll
    for (int q = 0; q < 4; ++q) {
        int lin = q * 256 + t;
        int r = lin >> 4;
        int c4 = (lin & 15) << 2;
        float4 v = *reinterpret_cast<const float4*>(src + (long)r * HH + c4);
        tile[r][c4 + 0] = v.x; tile[r][c4 + 1] = v.y;
        tile[r][c4 + 2] = v.z; tile[r][c4 + 3] = v.w;
    }
    __syncthreads();
    const int col = t >> 2;
    const int seg = t & 3;
    unsigned short h8[16], l8[16];
    #pragma unroll
    for (int j = 0; j < 16; ++j)
        split2(tile[seg * 16 + j][col], h8[j], l8[j]);
    int base = col * 128 + seg * 32;
    int swz  = (col & 7) << 4;
    *reinterpret_cast<u32x4*>((char*)dh_img + ((base +  0) ^ swz)) = *reinterpret_cast<u32x4*>(h8);
    *reinterpret_cast<u32x4*>((char*)dh_img + ((base + 16) ^ swz)) = *reinterpret_cast<u32x4*>(h8 + 8);
    *reinterpret_cast<u32x4*>((char*)dl_img + ((base +  0) ^ swz)) = *reinterpret_cast<u32x4*>(l8);
    *reinterpret_cast<u32x4*>((char*)dl_img + ((base + 16) ^ swz)) = *reinterpret_cast<u32x4*>(l8 + 8);
}

// ---------------------------------------------------------------------------
// LDS-staged GEMM. C[m] (1024x64) = A[m] (1024x1024) @ B (1024x64).
// Block 64 rows x 64 cols, 256 thr = 4 waves x 16 rows. LDS 32 KB -> 4/CU.
// MODE 0 (K1): write swizzled chunk images of C (hi/lo) only; block (0,0)
//              zeroes K2's per-sample counters.
// MODE 1 (K2): fused 8-iteration epilogue -> partials; last block per sample
//              (atomic counter) runs the decide phase for that sample.
// ---------------------------------------------------------------------------
template <int MODE>
__global__ __launch_bounds__(256, 4) void gemm_split(
    const float* __restrict__ A, long aStride,
    const unsigned short* __restrict__ Bh, const unsigned short* __restrict__ Bl,
    long bStrideH,                        // shorts per sample (0 = shared B)
    unsigned short* __restrict__ ChOut,   // image out (MODE 0 only)
    unsigned short* __restrict__ ClOut,
    float* __restrict__ partials,         // MODE 1
    int* __restrict__ counters,           // MODE 0: zero; MODE 1: arrive
    const float* __restrict__ fc_w,       // MODE 1 decide
    const float* __restrict__ fc_b,
    float* __restrict__ col0k,
    int* __restrict__ k_arr,
    float* __restrict__ out_feat,
    float* __restrict__ out_sr,
    float* __restrict__ out_b,
    float* __restrict__ out_u)
{
    __shared__ __align__(16) char smem[32768];
    unsigned short* Ahi = (unsigned short*)(smem);
    unsigned short* Alo = (unsigned short*)(smem + 8192);
    unsigned short* Bhi = (unsigned short*)(smem + 16384);
    unsigned short* Blo = (unsigned short*)(smem + 24576);

    const int m = blockIdx.y;
    const int row0 = blockIdx.x * 64;
    const float* A_m = A + (long)m * aStride + (long)row0 * NN;
    const unsigned short* bh_us = Bh + (bStrideH ? (long)m * bStrideH : 0L);
    const unsigned short* bl_us = Bl + (bStrideH ? (long)m * bStrideH : 0L);
    const u32x4* bh4 = reinterpret_cast<const u32x4*>(bh_us);
    const u32x4* bl4 = reinterpret_cast<const u32x4*>(bl_us);

    const int tid = threadIdx.x;
    const int w   = tid >> 6;
    const int l   = tid & 63;
    const int l15 = l & 15;
    const int lg  = l >> 4;

    if (MODE == 0 && blockIdx.x == 0 && blockIdx.y == 0 && tid < MS)
        counters[tid] = 0;

    f32x4 acc[4] = {};

    int lin_r[4], lin_c4[4];
    #pragma unroll
    for (int q = 0; q < 4; ++q) {
        int lin = q * 256 + tid;
        lin_r[q]  = lin >> 4;
        lin_c4[q] = (lin & 15) << 2;
    }

    // ---- prologue: load chunk 0 into regs ----
    f32x4 av[4];
    u32x4 bhreg[2], blreg[2];
    #pragma unroll
    for (int q = 0; q < 4; ++q) {
        const f32x4* p = reinterpret_cast<const f32x4*>(A_m + (long)lin_r[q] * NN + lin_c4[q]);
        av[q] = (MODE == 1) ? *p : __builtin_nontemporal_load(p);
    }
    bhreg[0] = bh4[tid];       bhreg[1] = bh4[256 + tid];
    blreg[0] = bl4[tid];       blreg[1] = bl4[256 + tid];

    for (int kc = 0; kc < 16; ++kc) {
        // ---- stage A (split) + B (raw copy) from regs into LDS ----
        #pragma unroll
        for (int q = 0; q < 4; ++q) {
            ushort4 h, lw;
            split2(av[q].x, h.x, lw.x);
            split2(av[q].y, h.y, lw.y);
            split2(av[q].z, h.z, lw.z);
            split2(av[q].w, h.w, lw.w);
            int byte = (lin_r[q] * 128 + lin_c4[q] * 2) ^ ((lin_r[q] & 7) << 4);
            *reinterpret_cast<ushort4*>((char*)Ahi + byte) = h;
            *reinterpret_cast<ushort4*>((char*)Alo + byte) = lw;
        }
        reinterpret_cast<u32x4*>(Bhi)[tid]       = bhreg[0];
        reinterpret_cast<u32x4*>(Bhi)[256 + tid] = bhreg[1];
        reinterpret_cast<u32x4*>(Blo)[tid]       = blreg[0];
        reinterpret_cast<u32x4*>(Blo)[256 + tid] = blreg[1];
        __syncthreads();

        // ---- issue next-chunk loads (latency hides under MFMA phase) ----
        if (kc < 15) {
            int ko = (kc + 1) * 64;
            #pragma unroll
            for (int q = 0; q < 4; ++q) {
                const f32x4* p = reinterpret_cast<const f32x4*>(A_m + (long)lin_r[q] * NN + ko + lin_c4[q]);
                av[q] = (MODE == 1) ? *p : __builtin_nontemporal_load(p);
            }
            int cb = (kc + 1) * 512;
            bhreg[0] = bh4[cb + tid];       bhreg[1] = bh4[cb + 256 + tid];
            blreg[0] = bl4[cb + tid];       blreg[1] = bl4[cb + 256 + tid];
        }

        // ---- MFMA: 2 k-slices of 32 ----
        #pragma unroll
        for (int s = 0; s < 2; ++s) {
            int arow  = w * 16 + l15;
            int abyte = (arow * 128 + s * 64 + lg * 16) ^ ((arow & 7) << 4);
            bf16x8 ah = *reinterpret_cast<bf16x8*>((char*)Ahi + abyte);
            bf16x8 al = *reinterpret_cast<bf16x8*>((char*)Alo + abyte);
            #pragma unroll
            for (int fc = 0; fc < 4; ++fc) {
                int col   = fc * 16 + l15;
                int bbyte = (col * 128 + s * 64 + lg * 16) ^ ((col & 7) << 4);
                bf16x8 bh8 = *reinterpret_cast<bf16x8*>((char*)Bhi + bbyte);
                bf16x8 bl8 = *reinterpret_cast<bf16x8*>((char*)Blo + bbyte);
                acc[fc] = __builtin_amdgcn_mfma_f32_16x16x32_bf16(ah, bh8, acc[fc], 0, 0, 0);
                acc[fc] = __builtin_amdgcn_mfma_f32_16x16x32_bf16(ah, bl8, acc[fc], 0, 0, 0);
                acc[fc] = __builtin_amdgcn_mfma_f32_16x16x32_bf16(al, bh8, acc[fc], 0, 0, 0);
            }
        }
        __syncthreads();
    }

    if constexpr (MODE == 0) {
        // ---- write swizzled hi/lo image for chunk blockIdx.x ----
        unsigned short* dh = ChOut + (long)m * HH * NN + (long)blockIdx.x * 4096;
        unsigned short* dl = ClOut + (long)m * HH * NN + (long)blockIdx.x * 4096;
        const int kb = (w * 16 + lg * 4) * 2;   // byte base of klocal run
        #pragma unroll
        for (int fc = 0; fc < 4; ++fc) {
            int col = fc * 16 + l15;
            ushort4 h4, l4;
            split2(acc[fc][0], h4.x, l4.x);
            split2(acc[fc][1], h4.y, l4.y);
            split2(acc[fc][2], h4.z, l4.z);
            split2(acc[fc][3], h4.w, l4.w);
            int byte = (col * 128 + kb) ^ ((col & 7) << 4);
            *reinterpret_cast<ushort4*>((char*)dh + byte) = h4;
            *reinterpret_cast<ushort4*>((char*)dl + byte) = l4;
        }
    } else {
        // ---- fused 8-iteration epilogue (scratch overlays staging LDS) ----
        float* red2 = (float*)(smem);          // [4][8][64] = 8 KB
        float* x0s  = (float*)(smem + 8192);   // 64 floats
        // x0s: XW[0][col] reconstructed from hi/lo image (chunk 0, klocal 0)
        if (tid < 64) {
            int byte = (tid * 128) ^ ((tid & 7) << 4);
            float hi = bf16_to_f32(bh_us[byte >> 1]);
            float lo = bf16_to_f32(bl_us[byte >> 1]);
            x0s[tid] = hi + lo;
        }
        __syncthreads();

        int grows[4]; float v[4], bc[4];
        #pragma unroll
        for (int r = 0; r < 4; ++r) {
            int lrow = w * 16 + lg * 4 + r;
            grows[r] = row0 + lrow;
            v[r] = A[(long)m * aStride + (long)grows[r] * NN];   // W0[row,0]
            bc[r] = 0.0f;
        }
        // xwv: XW[grows[r]][col] reconstructed from hi/lo images
        float xwv[4][4];
        #pragma unroll
        for (int fc = 0; fc < 4; ++fc) {
            int col = fc * 16 + l15;
            #pragma unroll
            for (int r = 0; r < 4; ++r) {
                int g = grows[r];
                long idx = ((long)(g >> 6) * 4096) +
                           (((col * 128 + (g & 63) * 2) ^ ((col & 7) << 4)) >> 1);
                xwv[fc][r] = bf16_to_f32(bh_us[idx]) + bf16_to_f32(bl_us[idx]);
            }
        }

        float alpha = 1.0f, gamma = 0.0f;
        #pragma unroll
        for (int t = 1; t <= 8; ++t) {
            #pragma unroll
            for (int r = 0; r < 4; ++r) {
                float c = (grows[r] < 5 * t && v[r] > 0.0f) ? (1.0f - v[r]) : 0.0f;
                bc[r] = 0.5f * (bc[r] + c);
                v[r]  = 0.5f * (v[r] + c) + (grows[r] == 0 ? 1.0f : 0.0f);
            }
            alpha *= 0.5f;
            gamma = 0.5f * gamma + 1.0f;
            #pragma unroll
            for (int fc = 0; fc < 4; ++fc) {
                float x0c = x0s[fc * 16 + l15];
                float s = 0.0f;
                #pragma unroll
                for (int r = 0; r < 4; ++r) {
                    float y = alpha * acc[fc][r] + bc[r] * x0c + gamma * xwv[fc][r];
                    s += (y >= 0.0f) ? y : SLOPEF * y;
                }
                s += __shfl_xor(s, 16);
                s += __shfl_xor(s, 32);
                if (l < 16) red2[(w * 8 + (t - 1)) * 64 + fc * 16 + l] = s;
            }
        }
        __syncthreads();
        if (tid < 512) {
            int t8 = tid >> 6, col = tid & 63;
            float p = red2[(0 * 8 + t8) * 64 + col] + red2[(1 * 8 + t8) * 64 + col] +
                      red2[(2 * 8 + t8) * 64 + col] + red2[(3 * 8 + t8) * 64 + col];
            partials[(((long)m * 16 + blockIdx.x) * 8 + t8) * 64 + col] = p;
        }

        // ---- last-block-per-sample decide ----
        __shared__ int lastFlag;
        __threadfence();
        __syncthreads();
        if (tid == 0) {
            int old = atomicAdd(&counters[m], 1);
            lastFlag = (old == 15);
        }
        __syncthreads();
        if (!lastFlag) return;
        __threadfence();

        float* feat   = (float*)(smem);            // [8][64] = 2 KB
        float* sr_all = (float*)(smem + 2048);     // [8][CC]
        float* Ss     = (float*)(smem + 2048 + 8 * CC * 4);
        float* us     = Ss + 8;
        int*   kshp   = (int*)(us + 8);

        for (int idx = tid; idx < 512; idx += 256) {
            int t8 = idx >> 6, col = idx & 63;
            float s = 0.0f;
            for (int bx = 0; bx < 16; ++bx)
                s += partials[(((long)m * 16 + bx) * 8 + t8) * 64 + col];
            feat[t8 * 64 + col] = s * (1.0f / NN);
        }
        __syncthreads();

        if (tid < 80) {
            int t8 = tid / 10, c = tid % 10;
            float a = fc_b[c];
            for (int h = 0; h < HH; ++h) a += feat[t8 * 64 + h] * fc_w[h * CC + c];
            sr_all[t8 * CC + c] = log1pf(expf(-fabsf(a))) + fmaxf(a, 0.0f);
        }
        __syncthreads();

        if (tid < 8) {
            float S = (float)CC;
            for (int c = 0; c < CC; ++c) S += sr_all[tid * CC + c];
            Ss[tid] = S;
            us[tid] = (float)CC / S;
        }
        __syncthreads();

        if (tid == 0) {
            float u0 = 999.0f; int k = 1;
            for (int tt = 1; tt <= 8; ++tt) {
                float u = us[tt - 1];
                int brk = (u >= u0) || (tt == 8);
                if (!brk) { k = tt; u0 = u; } else break;
            }
            kshp[0] = k;
            k_arr[m] = k;
            out_u[m] = us[k - 1];
        }
        __syncthreads();

        const int k = kshp[0];
        if (tid < 64) out_feat[m * HH + tid] = feat[(k - 1) * 64 + tid];
        if (tid < CC) {
            out_sr[m * CC + tid] = sr_all[(k - 1) * CC + tid];
            out_b[m * CC + tid]  = sr_all[(k - 1) * CC + tid] / Ss[k - 1];
        }
        for (int i = tid; i < NN; i += 256) {
            float vv = A[(long)m * aStride + (long)i * NN];
            for (int s = 1; s <= k; ++s) {
                float c = (i < 5 * s && vv > 0.0f) ? (1.0f - vv) : 0.0f;
                vv = 0.5f * (vv + c) + (i == 0 ? 1.0f : 0.0f);
            }
            col0k[m * NN + i] = vv;
        }
    }
}

// ---------------------------------------------------------------------------
// Final W: W_k = 0.5^k*W0 + diag(2(1-0.5^k)), col0 from sim.
// Grid-stride, nontemporal stores.
// ---------------------------------------------------------------------------
__global__ __launch_bounds__(256) void finalize_W(
    const float* __restrict__ W0, const float* __restrict__ col0k,
    const int* __restrict__ k_arr, float* __restrict__ outW)
{
    const long n4 = (long)MS * NN * NN / 4;
    const long stride = (long)gridDim.x * 256;
    for (long i4 = (long)blockIdx.x * 256 + threadIdx.x; i4 < n4; i4 += stride) {
        long e = i4 * 4;
        int m = (int)(e >> 20);
        int i = (int)((e >> 10) & 1023);
        int j = (int)(e & 1023);
        int k = k_arr[m];
        float scale = 1.0f / (float)(1 << k);
        float diagadd = 2.0f * (1.0f - scale);

        f32x4 wv = reinterpret_cast<const f32x4*>(W0)[i4];
        float v0 = scale * wv.x + ((i == j + 0) ? diagadd : 0.0f);
        float v1 = scale * wv.y + ((i == j + 1) ? diagadd : 0.0f);
        float v2 = scale * wv.z + ((i == j + 2) ? diagadd : 0.0f);
        float v3 = scale * wv.w + ((i == j + 3) ? diagadd : 0.0f);
        if (j == 0) v0 = col0k[m * NN + i];
        f32x4 o = {v0, v1, v2, v3};
        __builtin_nontemporal_store(o, reinterpret_cast<f32x4*>(outW) + i4);
    }
}

// ---------------------------------------------------------------------------
extern "C" void kernel_launch(void* const* d_in, const int* in_sizes, int n_in,
                              void* d_out, int out_size, void* d_ws, size_t ws_size,
                              hipStream_t stream)
{
    const float* features = (const float*)d_in[0];
    const float* weights  = (const float*)d_in[1];
    const float* w_gnn0   = (const float*)d_in[2];
    const float* w_gnn1   = (const float*)d_in[3];
    const float* w_gnn2   = (const float*)d_in[4];
    const float* fc_w     = (const float*)d_in[5];
    const float* fc_b     = (const float*)d_in[6];
    const int*   viewFlag = (const int*)d_in[7];

    float* out = (float*)d_out;
    float* out_feat = out;                                   // 32*64
    float* outW     = out + (long)MS * HH;                   // 32*1024*1024
    float* out_sr   = outW + (long)MS * NN * NN;             // 32*10
    float* out_b    = out_sr + MS * CC;                      // 32*10
    float* out_u    = out_b + MS * CC;                       // 32

    char* ws = (char*)d_ws;
    unsigned short* XWh   = (unsigned short*)ws;                     // 2M shorts
    unsigned short* XWl   = XWh + (long)MS * HH * NN;                // 2M shorts
    unsigned short* Wgh   = XWl + (long)MS * HH * NN;                // 64K shorts
    unsigned short* Wgl   = Wgh + (long)HH * NN;                     // 64K shorts
    float* partials       = (float*)(Wgl + (long)HH * NN);           // 256K floats
    float* col0k          = partials + (long)MS * 16 * 8 * 64;       // 32K floats
    int*   k_arr          = (int*)(col0k + (long)MS * NN);           // 32
    int*   counters       = k_arr + MS;                              // 32

    // S1: pre-split w_gnn (selected by view_flag) -> swizzled chunk images
    split_B_sel<<<16, 256, 0, stream>>>(w_gnn0, w_gnn1, w_gnn2, viewFlag, Wgh, Wgl);
    // K1: XW = features @ Wg -> swizzled images only (+ counter zeroing)
    dim3 gemmGrid(NN / 64, MS);
    gemm_split<0><<<gemmGrid, 256, 0, stream>>>(features, (long)NN * NN,
                                                Wgh, Wgl, 0L,
                                                XWh, XWl, nullptr, counters,
                                                nullptr, nullptr, nullptr, nullptr,
                                                nullptr, nullptr, nullptr, nullptr);
    // K2: Y0 = weights @ XW + fused epilogue -> partials + last-block decide
    gemm_split<1><<<gemmGrid, 256, 0, stream>>>(weights, (long)NN * NN,
                                                XWh, XWl, (long)HH * NN,
                                                nullptr, nullptr, partials, counters,
                                                fc_w, fc_b, col0k, k_arr,
                                                out_feat, out_sr, out_b, out_u);
    // K3: final W
    finalize_W<<<2048, 256, 0, stream>>>(weights, col0k, k_arr, outW);
}

// Round 9
// 121.089 us; speedup vs baseline: 1.3123x; 1.3123x over previous
//
#include <hip/hip_runtime.h>
#include <math.h>

#define MS 32
#define NN 1024
#define HH 64
#define CC 10
#define SLOPEF 0.2f

typedef __attribute__((ext_vector_type(8))) short bf16x8;
typedef __attribute__((ext_vector_type(4))) float f32x4;
typedef __attribute__((ext_vector_type(4))) unsigned int u32x4;

// Split fp32 into hi/lo bf16 (truncation; lo captures residual of hi).
__device__ __forceinline__ void split2(float v, unsigned short& hi, unsigned short& lo) {
    unsigned u = __builtin_bit_cast(unsigned, v);
    hi = (unsigned short)(u >> 16);
    float hf = __builtin_bit_cast(float, u & 0xFFFF0000u);
    float l = v - hf;
    lo = (unsigned short)(__builtin_bit_cast(unsigned, l) >> 16);
}

// ---------------------------------------------------------------------------
// Pre-split w_gnn into per-64k-chunk SWIZZLED LDS IMAGES (8 KB/chunk each
// for hi and lo). Image byte layout == gemm's LDS Bhi/Blo layout:
//   byte = (col*128 + k_local*2) ^ ((col&7)<<4)
// ---------------------------------------------------------------------------
__global__ __launch_bounds__(256) void split_B_sel(
    const float* __restrict__ B0, const float* __restrict__ B1,
    const float* __restrict__ B2, const int* __restrict__ flag,
    unsigned short* __restrict__ dh, unsigned short* __restrict__ dl)
{
    int vf = flag[0];
    const float* B = (vf == 0) ? B0 : (vf == 1 ? B1 : B2);
    int c = blockIdx.x;
    const float* src = B + (long)c * 64 * HH;
    unsigned short* dh_img = dh + (long)c * 4096;
    unsigned short* dl_img = dl + (long)c * 4096;

    __shared__ float tile[64][65];
    const int t = threadIdx.x;
    #pragma unroll
    for (int q = 0; q < 4; ++q) {
        int lin = q * 256 + t;
        int r = lin >> 4;
        int c4 = (lin & 15) << 2;
        float4 v = *reinterpret_cast<const float4*>(src + (long)r * HH + c4);
        tile[r][c4 + 0] = v.x; tile[r][c4 + 1] = v.y;
        tile[r][c4 + 2] = v.z; tile[r][c4 + 3] = v.w;
    }
    __syncthreads();
    const int col = t >> 2;
    const int seg = t & 3;
    unsigned short h8[16], l8[16];
    #pragma unroll
    for (int j = 0; j < 16; ++j)
        split2(tile[seg * 16 + j][col], h8[j], l8[j]);
    int base = col * 128 + seg * 32;
    int swz  = (col & 7) << 4;
    *reinterpret_cast<u32x4*>((char*)dh_img + ((base +  0) ^ swz)) = *reinterpret_cast<u32x4*>(h8);
    *reinterpret_cast<u32x4*>((char*)dh_img + ((base + 16) ^ swz)) = *reinterpret_cast<u32x4*>(h8 + 8);
    *reinterpret_cast<u32x4*>((char*)dl_img + ((base +  0) ^ swz)) = *reinterpret_cast<u32x4*>(l8);
    *reinterpret_cast<u32x4*>((char*)dl_img + ((base + 16) ^ swz)) = *reinterpret_cast<u32x4*>(l8 + 8);
}

// ---------------------------------------------------------------------------
// LDS-staged GEMM. C[m] (1024x64) = A[m] (1024x1024) @ B (1024x64).
// Block 64 rows x 64 cols, 256 thr = 4 waves x 16 rows. LDS exactly 32 KB
// (epilogue scratch overlays the staging buffers) -> 5 blocks/CU.
// MODE 0 (K1): write C fp32 + pre-split swizzled chunk images of C.
// MODE 1 (K2): fused 8-iteration epilogue -> partials.
// ---------------------------------------------------------------------------
template <int MODE>
__global__ __launch_bounds__(256, 5) void gemm_split(
    const float* __restrict__ A, long aStride,
    const unsigned short* __restrict__ Bh, const unsigned short* __restrict__ Bl,
    long bStrideH,                        // shorts per sample (0 = shared B)
    const float* __restrict__ XWf,        // fp32 XW (MODE 1 only)
    unsigned short* __restrict__ ChOut,   // image out (MODE 0 only)
    unsigned short* __restrict__ ClOut,
    float* __restrict__ Cmat)
{
    __shared__ __align__(16) char smem[32768];
    unsigned short* Ahi = (unsigned short*)(smem);
    unsigned short* Alo = (unsigned short*)(smem + 8192);
    unsigned short* Bhi = (unsigned short*)(smem + 16384);
    unsigned short* Blo = (unsigned short*)(smem + 24576);

    const int m = blockIdx.y;
    const int row0 = blockIdx.x * 64;
    const float* A_m = A + (long)m * aStride + (long)row0 * NN;
    const u32x4* bh4 = reinterpret_cast<const u32x4*>(Bh + (bStrideH ? (long)m * bStrideH : 0L));
    const u32x4* bl4 = reinterpret_cast<const u32x4*>(Bl + (bStrideH ? (long)m * bStrideH : 0L));

    const int tid = threadIdx.x;
    const int w   = tid >> 6;
    const int l   = tid & 63;
    const int l15 = l & 15;
    const int lg  = l >> 4;

    f32x4 acc[4] = {};

    int lin_r[4], lin_c4[4];
    #pragma unroll
    for (int q = 0; q < 4; ++q) {
        int lin = q * 256 + tid;
        lin_r[q]  = lin >> 4;
        lin_c4[q] = (lin & 15) << 2;
    }

    // ---- prologue: load chunk 0 into regs ----
    f32x4 av[4];
    u32x4 bhreg[2], blreg[2];
    #pragma unroll
    for (int q = 0; q < 4; ++q) {
        const f32x4* p = reinterpret_cast<const f32x4*>(A_m + (long)lin_r[q] * NN + lin_c4[q]);
        av[q] = (MODE == 1) ? *p : __builtin_nontemporal_load(p);
    }
    bhreg[0] = bh4[tid];       bhreg[1] = bh4[256 + tid];
    blreg[0] = bl4[tid];       blreg[1] = bl4[256 + tid];

    for (int kc = 0; kc < 16; ++kc) {
        // ---- stage A (split) + B (raw copy) from regs into LDS ----
        #pragma unroll
        for (int q = 0; q < 4; ++q) {
            ushort4 h, lw;
            split2(av[q].x, h.x, lw.x);
            split2(av[q].y, h.y, lw.y);
            split2(av[q].z, h.z, lw.z);
            split2(av[q].w, h.w, lw.w);
            int byte = (lin_r[q] * 128 + lin_c4[q] * 2) ^ ((lin_r[q] & 7) << 4);
            *reinterpret_cast<ushort4*>((char*)Ahi + byte) = h;
            *reinterpret_cast<ushort4*>((char*)Alo + byte) = lw;
        }
        reinterpret_cast<u32x4*>(Bhi)[tid]       = bhreg[0];
        reinterpret_cast<u32x4*>(Bhi)[256 + tid] = bhreg[1];
        reinterpret_cast<u32x4*>(Blo)[tid]       = blreg[0];
        reinterpret_cast<u32x4*>(Blo)[256 + tid] = blreg[1];
        __syncthreads();

        // ---- issue next-chunk loads (latency hides under MFMA phase) ----
        if (kc < 15) {
            int ko = (kc + 1) * 64;
            #pragma unroll
            for (int q = 0; q < 4; ++q) {
                const f32x4* p = reinterpret_cast<const f32x4*>(A_m + (long)lin_r[q] * NN + ko + lin_c4[q]);
                av[q] = (MODE == 1) ? *p : __builtin_nontemporal_load(p);
            }
            int cb = (kc + 1) * 512;
            bhreg[0] = bh4[cb + tid];       bhreg[1] = bh4[cb + 256 + tid];
            blreg[0] = bl4[cb + tid];       blreg[1] = bl4[cb + 256 + tid];
        }

        // ---- MFMA: 2 k-slices of 32 ----
        #pragma unroll
        for (int s = 0; s < 2; ++s) {
            int arow  = w * 16 + l15;
            int abyte = (arow * 128 + s * 64 + lg * 16) ^ ((arow & 7) << 4);
            bf16x8 ah = *reinterpret_cast<bf16x8*>((char*)Ahi + abyte);
            bf16x8 al = *reinterpret_cast<bf16x8*>((char*)Alo + abyte);
            #pragma unroll
            for (int fc = 0; fc < 4; ++fc) {
                int col   = fc * 16 + l15;
                int bbyte = (col * 128 + s * 64 + lg * 16) ^ ((col & 7) << 4);
                bf16x8 bh8 = *reinterpret_cast<bf16x8*>((char*)Bhi + bbyte);
                bf16x8 bl8 = *reinterpret_cast<bf16x8*>((char*)Blo + bbyte);
                acc[fc] = __builtin_amdgcn_mfma_f32_16x16x32_bf16(ah, bh8, acc[fc], 0, 0, 0);
                acc[fc] = __builtin_amdgcn_mfma_f32_16x16x32_bf16(ah, bl8, acc[fc], 0, 0, 0);
                acc[fc] = __builtin_amdgcn_mfma_f32_16x16x32_bf16(al, bh8, acc[fc], 0, 0, 0);
            }
        }
        __syncthreads();
    }

    if constexpr (MODE == 0) {
        // ---- write C fp32 + swizzled hi/lo image for chunk blockIdx.x ----
        float* C_m = Cmat + (long)m * NN * HH + (long)row0 * HH;
        unsigned short* dh = ChOut + (long)m * HH * NN + (long)blockIdx.x * 4096;
        unsigned short* dl = ClOut + (long)m * HH * NN + (long)blockIdx.x * 4096;
        const int kb = (w * 16 + lg * 4) * 2;   // byte base of klocal run
        #pragma unroll
        for (int fc = 0; fc < 4; ++fc) {
            int col = fc * 16 + l15;
            ushort4 h4, l4;
            split2(acc[fc][0], h4.x, l4.x);
            split2(acc[fc][1], h4.y, l4.y);
            split2(acc[fc][2], h4.z, l4.z);
            split2(acc[fc][3], h4.w, l4.w);
            #pragma unroll
            for (int r = 0; r < 4; ++r) {
                int row = w * 16 + lg * 4 + r;
                C_m[(long)row * HH + col] = acc[fc][r];
            }
            int byte = (col * 128 + kb) ^ ((col & 7) << 4);
            *reinterpret_cast<ushort4*>((char*)dh + byte) = h4;
            *reinterpret_cast<ushort4*>((char*)dl + byte) = l4;
        }
    } else {
        // ---- fused 8-iteration epilogue (scratch overlays staging LDS) ----
        float* red2 = (float*)(smem);          // [4][8][64] = 8 KB
        float* x0s  = (float*)(smem + 8192);   // 64 floats
        const float* XWm = XWf + (long)m * NN * HH;
        if (tid < 64) x0s[tid] = XWm[tid];
        __syncthreads();

        int grows[4]; float v[4], bc[4];
        #pragma unroll
        for (int r = 0; r < 4; ++r) {
            int lrow = w * 16 + lg * 4 + r;
            grows[r] = row0 + lrow;
            v[r] = A[(long)m * aStride + (long)grows[r] * NN];   // W0[row,0]
            bc[r] = 0.0f;
        }
        float xwv[4][4];
        #pragma unroll
        for (int fc = 0; fc < 4; ++fc) {
            int col = fc * 16 + l15;
            #pragma unroll
            for (int r = 0; r < 4; ++r)
                xwv[fc][r] = XWm[(long)grows[r] * HH + col];
        }

        float alpha = 1.0f, gamma = 0.0f;
        #pragma unroll
        for (int t = 1; t <= 8; ++t) {
            #pragma unroll
            for (int r = 0; r < 4; ++r) {
                float c = (grows[r] < 5 * t && v[r] > 0.0f) ? (1.0f - v[r]) : 0.0f;
                bc[r] = 0.5f * (bc[r] + c);
                v[r]  = 0.5f * (v[r] + c) + (grows[r] == 0 ? 1.0f : 0.0f);
            }
            alpha *= 0.5f;
            gamma = 0.5f * gamma + 1.0f;
            #pragma unroll
            for (int fc = 0; fc < 4; ++fc) {
                float x0c = x0s[fc * 16 + l15];
                float s = 0.0f;
                #pragma unroll
                for (int r = 0; r < 4; ++r) {
                    float y = alpha * acc[fc][r] + bc[r] * x0c + gamma * xwv[fc][r];
                    s += (y >= 0.0f) ? y : SLOPEF * y;
                }
                s += __shfl_xor(s, 16);
                s += __shfl_xor(s, 32);
                if (l < 16) red2[(w * 8 + (t - 1)) * 64 + fc * 16 + l] = s;
            }
        }
        __syncthreads();
        if (tid < 512) {
            int t8 = tid >> 6, col = tid & 63;
            float p = red2[(0 * 8 + t8) * 64 + col] + red2[(1 * 8 + t8) * 64 + col] +
                      red2[(2 * 8 + t8) * 64 + col] + red2[(3 * 8 + t8) * 64 + col];
            Cmat[(((long)m * 16 + blockIdx.x) * 8 + t8) * 64 + col] = p;
        }
    }
}

// ---------------------------------------------------------------------------
// Per-sample decision: reduce partials -> feat_t -> sr_t -> u_t, break scan,
// write small outputs + col0 simulation.
// ---------------------------------------------------------------------------
__global__ __launch_bounds__(512) void decide_kernel(
    const float* __restrict__ partials,
    const float* __restrict__ weights,
    const float* __restrict__ fc_w,
    const float* __restrict__ fc_b,
    float* __restrict__ col0k,
    int* __restrict__ k_arr,
    float* __restrict__ out_feat,
    float* __restrict__ out_sr,
    float* __restrict__ out_b,
    float* __restrict__ out_u)
{
    __shared__ float feat[8][64];
    __shared__ float sr_all[8][CC];
    __shared__ float Ss[8], us[8];
    __shared__ int ksh;

    const int m = blockIdx.x;
    const int tid = threadIdx.x;

    {
        int t8 = tid >> 6, col = tid & 63;
        float s = 0.0f;
        for (int bx = 0; bx < 16; ++bx)
            s += partials[(((long)m * 16 + bx) * 8 + t8) * 64 + col];
        feat[t8][col] = s * (1.0f / NN);
    }
    __syncthreads();

    if (tid < 80) {
        int t8 = tid / 10, c = tid % 10;
        float a = fc_b[c];
        for (int h = 0; h < HH; ++h) a += feat[t8][h] * fc_w[h * CC + c];
        sr_all[t8][c] = log1pf(expf(-fabsf(a))) + fmaxf(a, 0.0f);
    }
    __syncthreads();

    if (tid < 8) {
        float S = (float)CC;
        for (int c = 0; c < CC; ++c) S += sr_all[tid][c];
        Ss[tid] = S;
        us[tid] = (float)CC / S;
    }
    __syncthreads();

    if (tid == 0) {
        float u0 = 999.0f; int k = 1;
        for (int tt = 1; tt <= 8; ++tt) {
            float u = us[tt - 1];
            int brk = (u >= u0) || (tt == 8);
            if (!brk) { k = tt; u0 = u; } else break;
        }
        ksh = k;
        k_arr[m] = k;
        out_u[m] = us[k - 1];
    }
    __syncthreads();

    const int k = ksh;
    if (tid < 64) out_feat[m * HH + tid] = feat[k - 1][tid];
    if (tid < CC) {
        out_sr[m * CC + tid] = sr_all[k - 1][tid];
        out_b[m * CC + tid]  = sr_all[k - 1][tid] / Ss[k - 1];
    }
    for (int i = tid; i < NN; i += 512) {
        float v = weights[(long)m * NN * NN + (long)i * NN];
        for (int s = 1; s <= k; ++s) {
            float c = (i < 5 * s && v > 0.0f) ? (1.0f - v) : 0.0f;
            v = 0.5f * (v + c) + (i == 0 ? 1.0f : 0.0f);
        }
        col0k[m * NN + i] = v;
    }
}

// ---------------------------------------------------------------------------
// Final W: W_k = 0.5^k*W0 + diag(2(1-0.5^k)), col0 from sim.
// Grid-stride, nontemporal stores.
// ---------------------------------------------------------------------------
__global__ __launch_bounds__(256) void finalize_W(
    const float* __restrict__ W0, const float* __restrict__ col0k,
    const int* __restrict__ k_arr, float* __restrict__ outW)
{
    const long n4 = (long)MS * NN * NN / 4;
    const long stride = (long)gridDim.x * 256;
    for (long i4 = (long)blockIdx.x * 256 + threadIdx.x; i4 < n4; i4 += stride) {
        long e = i4 * 4;
        int m = (int)(e >> 20);
        int i = (int)((e >> 10) & 1023);
        int j = (int)(e & 1023);
        int k = k_arr[m];
        float scale = 1.0f / (float)(1 << k);
        float diagadd = 2.0f * (1.0f - scale);

        f32x4 wv = reinterpret_cast<const f32x4*>(W0)[i4];
        float v0 = scale * wv.x + ((i == j + 0) ? diagadd : 0.0f);
        float v1 = scale * wv.y + ((i == j + 1) ? diagadd : 0.0f);
        float v2 = scale * wv.z + ((i == j + 2) ? diagadd : 0.0f);
        float v3 = scale * wv.w + ((i == j + 3) ? diagadd : 0.0f);
        if (j == 0) v0 = col0k[m * NN + i];
        f32x4 o = {v0, v1, v2, v3};
        __builtin_nontemporal_store(o, reinterpret_cast<f32x4*>(outW) + i4);
    }
}

// ---------------------------------------------------------------------------
extern "C" void kernel_launch(void* const* d_in, const int* in_sizes, int n_in,
                              void* d_out, int out_size, void* d_ws, size_t ws_size,
                              hipStream_t stream)
{
    const float* features = (const float*)d_in[0];
    const float* weights  = (const float*)d_in[1];
    const float* w_gnn0   = (const float*)d_in[2];
    const float* w_gnn1   = (const float*)d_in[3];
    const float* w_gnn2   = (const float*)d_in[4];
    const float* fc_w     = (const float*)d_in[5];
    const float* fc_b     = (const float*)d_in[6];
    const int*   viewFlag = (const int*)d_in[7];

    float* out = (float*)d_out;
    float* out_feat = out;                                   // 32*64
    float* outW     = out + (long)MS * HH;                   // 32*1024*1024
    float* out_sr   = outW + (long)MS * NN * NN;             // 32*10
    float* out_b    = out_sr + MS * CC;                      // 32*10
    float* out_u    = out_b + MS * CC;                       // 32

    float* wsf = (float*)d_ws;
    float* XWf            = wsf;                             // 2M floats
    unsigned short* XWh   = (unsigned short*)(XWf + (long)MS * NN * HH);   // 2M shorts
    unsigned short* XWl   = XWh + (long)MS * HH * NN;                      // 2M shorts
    unsigned short* Wgh   = XWl + (long)MS * HH * NN;                      // 64K shorts
    unsigned short* Wgl   = Wgh + (long)HH * NN;                           // 64K shorts
    float* partials       = (float*)(Wgl + (long)HH * NN);                 // 256K floats
    float* col0k          = partials + (long)MS * 16 * 8 * 64;             // 32K floats
    int*   k_arr          = (int*)(col0k + (long)MS * NN);                 // 32

    // S1: pre-split w_gnn (selected by view_flag) -> swizzled chunk images
    split_B_sel<<<16, 256, 0, stream>>>(w_gnn0, w_gnn1, w_gnn2, viewFlag, Wgh, Wgl);
    // K1: XW = features @ Wg  (+ direct pre-split image write)
    dim3 gemmGrid(NN / 64, MS);
    gemm_split<0><<<gemmGrid, 256, 0, stream>>>(features, (long)NN * NN,
                                                Wgh, Wgl, 0L, nullptr,
                                                XWh, XWl, XWf);
    // K2: Y0 = weights @ XW + fused 8-iteration epilogue -> partials
    gemm_split<1><<<gemmGrid, 256, 0, stream>>>(weights, (long)NN * NN,
                                                XWh, XWl, (long)HH * NN, XWf,
                                                nullptr, nullptr, partials);
    // K3: decision + col0 sim
    decide_kernel<<<MS, 512, 0, stream>>>(partials, weights, fc_w, fc_b,
                                          col0k, k_arr,
                                          out_feat, out_sr, out_b, out_u);
    // K4: final W
    finalize_W<<<2048, 256, 0, stream>>>(weights, col0k, k_arr, outW);
}